// Round 6
// baseline (98.986 us; speedup 1.0000x reference)
//
#include <hip/hip_runtime.h>

// JPEG layer: rgb->ycbcr (clamped) -> 8x8 2-D DCT.
// B=32, C=3, H=W=512 -> out [32,3,64,64,8,8] f32.
//
// v6: barrier-free fine-grained decomposition. Evidence from v4/v5: dur is
// proportional to WRITE_SIZE at a fixed ~2.85 TB/s write rate (v4 104.9MB/
// 37.1us, v5 116.1MB/40.5us) -> write-stream-bound, 10% below the copy
// bench's 3.15 TB/s write side. v4's stores burst in phase C between
// barriers; this version uses 6144 single-wave WGs (blockIdx=(c,strip)) with
// NO barriers: each wave pipelines row loads, does both DCT stages in regs,
// transposes through a private 5KB LDS buffer, and stores full 64B lines
// continuously -> steadier write stream. Channel triples are blockIdx-
// adjacent so the 3x logical input reads stay temporally local in L3.
// nt stores reverted (v5: +11MB WRITE_SIZE, FETCH unchanged -> harmful).

#define HW (512 * 512)
#define COFF (128.0f / 255.0f)

__device__ constexpr float DM[8][8] = {
    { 0.353553391f,  0.353553391f,  0.353553391f,  0.353553391f,
      0.353553391f,  0.353553391f,  0.353553391f,  0.353553391f },
    { 0.490392640f,  0.415734806f,  0.277785115f,  0.097545161f,
     -0.097545161f, -0.277785115f, -0.415734806f, -0.490392640f },
    { 0.461939766f,  0.191341716f, -0.191341716f, -0.461939766f,
     -0.461939766f, -0.191341716f,  0.191341716f,  0.461939766f },
    { 0.415734806f, -0.097545161f, -0.490392640f, -0.277785115f,
      0.277785115f,  0.490392640f,  0.097545161f, -0.415734806f },
    { 0.353553391f, -0.353553391f, -0.353553391f,  0.353553391f,
      0.353553391f, -0.353553391f, -0.353553391f,  0.353553391f },
    { 0.277785115f, -0.490392640f,  0.097545161f,  0.415734806f,
     -0.415734806f, -0.097545161f,  0.490392640f, -0.277785115f },
    { 0.191341716f, -0.461939766f,  0.461939766f, -0.191341716f,
     -0.191341716f,  0.461939766f, -0.461939766f,  0.191341716f },
    { 0.097545161f, -0.277785115f,  0.415734806f, -0.490392640f,
      0.490392640f, -0.415734806f,  0.277785115f, -0.097545161f }
};

__device__ __forceinline__ float clamp01(float v) {
    return fminf(fmaxf(v, 0.0f), 1.0f);
}

// grid = (3, 2048): x = channel, y = strip (b, bh). 64 threads = 1 wave.
// lane = block column. Consecutive linear blockIdx = 3 channels of a strip.
__global__ __launch_bounds__(64, 3) void jpeg_dct(const float* __restrict__ rgb,
                                                  float* __restrict__ out) {
    __shared__ __align__(16) float tr[64][20];  // wave-private transpose, 5120 B

    const int c     = blockIdx.x;   // 0..2 output channel
    const int strip = blockIdx.y;   // 0..2047
    const int b     = strip >> 6;
    const int bh    = strip & 63;
    const int lane  = threadIdx.x;  // block column bw

    const float* base = rgb + (size_t)b * 3 * HW + (size_t)(bh * 8) * 512 + lane * 8;

    // channel coefficients (wave-uniform branch)
    float k0, k1, k2, off;
    if (c == 0)      { k0 = 0.299f;         k1 = 0.587f;         k2 = 0.114f;         off = 0.0f; }
    else if (c == 1) { k0 = -0.168735892f;  k1 = -0.331264108f;  k2 = 0.5f;           off = COFF; }
    else             { k0 = 0.5f;           k1 = -0.418687589f;  k2 = -0.081312411f;  off = COFF; }

    // double-buffered row loads: slot j&1 holds row j; row j+1 issued before
    // row j is consumed (all indices compile-time after full unroll).
    float4 Rb[2][2], Gb[2][2], Bb[2][2];
    {
        const float* p = base;
        Rb[0][0] = *(const float4*)(p);          Rb[0][1] = *(const float4*)(p + 4);
        Gb[0][0] = *(const float4*)(p + HW);     Gb[0][1] = *(const float4*)(p + HW + 4);
        Bb[0][0] = *(const float4*)(p + 2*HW);   Bb[0][1] = *(const float4*)(p + 2*HW + 4);
    }

    float T[8][8];  // T = D @ X
    #pragma unroll
    for (int i = 0; i < 8; i++)
        #pragma unroll
        for (int k = 0; k < 8; k++) T[i][k] = 0.0f;

    #pragma unroll
    for (int j = 0; j < 8; j++) {
        const int s = j & 1;
        if (j < 7) {
            const int n = s ^ 1;
            const float* p = base + (j + 1) * 512;
            Rb[n][0] = *(const float4*)(p);          Rb[n][1] = *(const float4*)(p + 4);
            Gb[n][0] = *(const float4*)(p + HW);     Gb[n][1] = *(const float4*)(p + HW + 4);
            Bb[n][0] = *(const float4*)(p + 2*HW);   Bb[n][1] = *(const float4*)(p + 2*HW + 4);
        }
        const float rv[8] = {Rb[s][0].x, Rb[s][0].y, Rb[s][0].z, Rb[s][0].w,
                             Rb[s][1].x, Rb[s][1].y, Rb[s][1].z, Rb[s][1].w};
        const float gv[8] = {Gb[s][0].x, Gb[s][0].y, Gb[s][0].z, Gb[s][0].w,
                             Gb[s][1].x, Gb[s][1].y, Gb[s][1].z, Gb[s][1].w};
        const float bv[8] = {Bb[s][0].x, Bb[s][0].y, Bb[s][0].z, Bb[s][0].w,
                             Bb[s][1].x, Bb[s][1].y, Bb[s][1].z, Bb[s][1].w};
        float x[8];
        #pragma unroll
        for (int k = 0; k < 8; k++) {
            x[k] = clamp01(fmaf(k0, rv[k], fmaf(k1, gv[k], fmaf(k2, bv[k], off)))) - COFF;
        }
        #pragma unroll
        for (int i = 0; i < 8; i++) {
            const float d = DM[i][j];
            #pragma unroll
            for (int k = 0; k < 8; k++) T[i][k] = fmaf(d, x[k], T[i][k]);
        }
    }

    // stage-2 DCT + wave-local LDS transpose -> full-64B-line stores.
    float* base2 = out + (size_t)((b * 3 + c) * 64 + bh) * 4096;

    #pragma unroll
    for (int r = 0; r < 4; r++) {
        #pragma unroll
        for (int ii = 0; ii < 2; ii++) {
            const int i = r * 2 + ii;
            float o[8];
            #pragma unroll
            for (int l = 0; l < 8; l++) {
                float s = T[i][0] * DM[l][0];
                #pragma unroll
                for (int k = 1; k < 8; k++) s = fmaf(T[i][k], DM[l][k], s);
                o[l] = s;
            }
            *(float4*)&tr[lane][ii * 8]     = make_float4(o[0], o[1], o[2], o[3]);
            *(float4*)&tr[lane][ii * 8 + 4] = make_float4(o[4], o[5], o[6], o[7]);
        }
        // wave-local write->read turn (single wave per WG; DS ops in-order)
        asm volatile("s_waitcnt lgkmcnt(0)" ::: "memory");
        #pragma unroll
        for (int s2 = 0; s2 < 4; s2++) {
            const int bws = s2 * 16 + (lane >> 2);   // source block-column
            const int mq  = (lane & 3) * 4;          // coef quad within round
            const float4 v = *(const float4*)&tr[bws][mq];
            *(float4*)(base2 + bws * 64 + r * 16 + mq) = v;
        }
        // WAR guard before next round's tr writes
        asm volatile("s_waitcnt lgkmcnt(0)" ::: "memory");
    }
}

extern "C" void kernel_launch(void* const* d_in, const int* in_sizes, int n_in,
                              void* d_out, int out_size, void* d_ws, size_t ws_size,
                              hipStream_t stream) {
    const float* rgb = (const float*)d_in[0];
    float* out = (float*)d_out;
    jpeg_dct<<<dim3(3, 2048), dim3(64), 0, stream>>>(rgb, out);
}

// Round 7
// 37.007 us; speedup vs baseline: 2.6748x; 2.6748x over previous
//
#include <hip/hip_runtime.h>
#include <hip/hip_fp16.h>

// JPEG layer: rgb->ycbcr (clamped) -> 8x8 2-D DCT.
// B=32, C=3, H=W=512 -> out [32,3,64,64,8,8] f32.
//
// v7 = v4 revert (proven best, 37.1 us). Ladder: 56.6 (v1 naive-coalesced)
// -> 50.7 (v2 cooperative LDS staging, kills 3x channel re-reads)
// -> 47.1 (v3 fp16 staging, 24 KB LDS, occupancy 18->27%)
// -> 37.1 (v4 LDS-transpose epilogue: every store instr covers 16 FULL 64 B
//          lines; write rate 2.15 -> 2.83 TB/s = 90% of copy-bench write side)
// Rejected with counter evidence:
//   v5 nontemporal stores: FETCH unchanged (49 MB), WRITE +11 MB, dur +3.4 us.
//   v6 barrier-free 1-wave WGs: FETCH 49 -> 268 MB (L3 did NOT absorb 3x
//      channel re-reads across XCDs), dur 98.9 us.
// Remaining gap to the demonstrated 3.15 TB/s write ceiling is ~12%; both
// structural attempts to capture it regressed -> this is the practical
// write-stream roofline for this op (compulsory 101 MB output write).

#define HW (512 * 512)

__device__ constexpr float DM[8][8] = {
    { 0.353553391f,  0.353553391f,  0.353553391f,  0.353553391f,
      0.353553391f,  0.353553391f,  0.353553391f,  0.353553391f },
    { 0.490392640f,  0.415734806f,  0.277785115f,  0.097545161f,
     -0.097545161f, -0.277785115f, -0.415734806f, -0.490392640f },
    { 0.461939766f,  0.191341716f, -0.191341716f, -0.461939766f,
     -0.461939766f, -0.191341716f,  0.191341716f,  0.461939766f },
    { 0.415734806f, -0.097545161f, -0.490392640f, -0.277785115f,
      0.277785115f,  0.490392640f,  0.097545161f, -0.415734806f },
    { 0.353553391f, -0.353553391f, -0.353553391f,  0.353553391f,
      0.353553391f, -0.353553391f, -0.353553391f,  0.353553391f },
    { 0.277785115f, -0.490392640f,  0.097545161f,  0.415734806f,
     -0.415734806f, -0.097545161f,  0.490392640f, -0.277785115f },
    { 0.191341716f, -0.461939766f,  0.461939766f, -0.191341716f,
     -0.191341716f,  0.461939766f, -0.461939766f,  0.191341716f },
    { 0.097545161f, -0.277785115f,  0.415734806f, -0.490392640f,
      0.490392640f, -0.415734806f,  0.277785115f, -0.097545161f }
};

__device__ __forceinline__ float clamp01(float v) {
    return fminf(fmaxf(v, 0.0f), 1.0f);
}

#define COFF (128.0f / 255.0f)

__device__ __forceinline__ void convert_quad(float4 r, float4 g, float4 bl,
                                             float4& y, float4& cb, float4& cr) {
    const float rv[4] = {r.x, r.y, r.z, r.w};
    const float gv[4] = {g.x, g.y, g.z, g.w};
    const float bv[4] = {bl.x, bl.y, bl.z, bl.w};
    float yo[4], cbo[4], cro[4];
    #pragma unroll
    for (int k = 0; k < 4; k++) {
        yo[k]  = clamp01(fmaf(0.299f, rv[k], fmaf(0.587f, gv[k], 0.114f * bv[k]))) - COFF;
        cbo[k] = clamp01(fmaf(-0.168735892f, rv[k],
                        fmaf(-0.331264108f, gv[k], fmaf(0.5f, bv[k], COFF)))) - COFF;
        cro[k] = clamp01(fmaf(0.5f, rv[k],
                        fmaf(-0.418687589f, gv[k], fmaf(-0.081312411f, bv[k], COFF)))) - COFF;
    }
    y  = make_float4(yo[0], yo[1], yo[2], yo[3]);
    cb = make_float4(cbo[0], cbo[1], cbo[2], cbo[3]);
    cr = make_float4(cro[0], cro[1], cro[2], cro[3]);
}

__device__ __forceinline__ void store_half4(__half* p, float4 v) {
    __half2* hp = (__half2*)p;
    hp[0] = __float22half2_rn(make_float2(v.x, v.y));
    hp[1] = __float22half2_rn(make_float2(v.z, v.w));
}

// 2048 WGs = (b, block_row). 192 threads = 3 waves.
// Phase A: cooperative fp16 ycbcr staging. Phase B: per-lane 8x8 DCT.
// Phase C: per-wave LDS transpose -> line-coalesced stores (reuses phase-A LDS).
__global__ __launch_bounds__(192, 4) void jpeg_dct(const float* __restrict__ rgb,
                                                   float* __restrict__ out) {
    __shared__ __align__(16) char smraw[24576];
    __half (*in)[8][512] = (__half (*)[8][512])smraw;   // [3][8][512] fp16, 24576 B
    float  (*tr)[64][20] = (float  (*)[64][20])smraw;   // [3][64][20]  f32, 15360 B

    const int wg = blockIdx.x;
    const int b  = wg >> 6;          // batch
    const int bh = wg & 63;          // block row
    const int t  = threadIdx.x;

    const float* rbase = rgb + (size_t)b * 3 * HW + (size_t)(bh * 8) * 512;

    // ---- Phase A: stage 1024 pixel-quads; thread t owns quads t, t+192, ... ----
    float4 R[6], G[6], Bv[6];
    #pragma unroll
    for (int it = 0; it < 5; it++) {
        const int q = t + it * 192;
        const int row = q >> 7, col4 = (q & 127) << 2;
        const float* p = rbase + row * 512 + col4;
        R[it]  = *(const float4*)(p);
        G[it]  = *(const float4*)(p + HW);
        Bv[it] = *(const float4*)(p + 2 * HW);
    }
    const bool extra = (t < 64);
    if (extra) {
        const int q = t + 960;
        const int row = q >> 7, col4 = (q & 127) << 2;
        const float* p = rbase + row * 512 + col4;
        R[5]  = *(const float4*)(p);
        G[5]  = *(const float4*)(p + HW);
        Bv[5] = *(const float4*)(p + 2 * HW);
    }
    #pragma unroll
    for (int it = 0; it < 5; it++) {
        const int q = t + it * 192;
        const int row = q >> 7, col4 = (q & 127) << 2;
        float4 y, cb, cr;
        convert_quad(R[it], G[it], Bv[it], y, cb, cr);
        store_half4(&in[0][row][col4], y);
        store_half4(&in[1][row][col4], cb);
        store_half4(&in[2][row][col4], cr);
    }
    if (extra) {
        const int q = t + 960;
        const int row = q >> 7, col4 = (q & 127) << 2;
        float4 y, cb, cr;
        convert_quad(R[5], G[5], Bv[5], y, cb, cr);
        store_half4(&in[0][row][col4], y);
        store_half4(&in[1][row][col4], cb);
        store_half4(&in[2][row][col4], cr);
    }
    __syncthreads();

    // ---- Phase B: wave c, lane bw -> stage-1 DCT (T = D @ X) from LDS ----
    const int c    = t >> 6;
    const int lane = t & 63;   // block column bw

    float T[8][8];
    #pragma unroll
    for (int i = 0; i < 8; i++)
        #pragma unroll
        for (int k = 0; k < 8; k++) T[i][k] = 0.0f;

    #pragma unroll
    for (int j = 0; j < 8; j++) {
        float4 raw = *(const float4*)&in[c][j][lane * 8];
        const __half2* hp = (const __half2*)&raw;
        float2 f0 = __half22float2(hp[0]);
        float2 f1 = __half22float2(hp[1]);
        float2 f2 = __half22float2(hp[2]);
        float2 f3 = __half22float2(hp[3]);
        const float x[8] = {f0.x, f0.y, f1.x, f1.y, f2.x, f2.y, f3.x, f3.y};
        #pragma unroll
        for (int i = 0; i < 8; i++) {
            const float d = DM[i][j];
            #pragma unroll
            for (int k = 0; k < 8; k++) T[i][k] = fmaf(d, x[k], T[i][k]);
        }
    }

    // all input-LDS reads done; LDS is re-purposed as transpose buffers
    __syncthreads();

    // ---- Phase C: stage-2 DCT, 2 output rows per round, transpose via LDS ----
    float* base2 = out + (size_t)((b * 3 + c) * 64 + bh) * 4096;

    #pragma unroll
    for (int r = 0; r < 4; r++) {
        #pragma unroll
        for (int ii = 0; ii < 2; ii++) {
            const int i = r * 2 + ii;
            float o[8];
            #pragma unroll
            for (int l = 0; l < 8; l++) {
                float s = T[i][0] * DM[l][0];
                #pragma unroll
                for (int k = 1; k < 8; k++) s = fmaf(T[i][k], DM[l][k], s);
                o[l] = s;
            }
            *(float4*)&tr[c][lane][ii * 8]     = make_float4(o[0], o[1], o[2], o[3]);
            *(float4*)&tr[c][lane][ii * 8 + 4] = make_float4(o[4], o[5], o[6], o[7]);
        }
        // wave-local write->read turn: all 16 source lanes' data in LDS
        asm volatile("s_waitcnt lgkmcnt(0)" ::: "memory");
        // read transposed, store full 64B lines: instr s covers 16 lines
        #pragma unroll
        for (int s = 0; s < 4; s++) {
            const int bws = s * 16 + (lane >> 2);      // source block-column
            const int mq  = (lane & 3) * 4;            // coef quad within round
            const float4 v = *(const float4*)&tr[c][bws][mq];
            *(float4*)(base2 + bws * 64 + r * 16 + mq) = v;
        }
        // WAR guard: reads of this round complete before next round's writes
        asm volatile("s_waitcnt lgkmcnt(0)" ::: "memory");
    }
}

extern "C" void kernel_launch(void* const* d_in, const int* in_sizes, int n_in,
                              void* d_out, int out_size, void* d_ws, size_t ws_size,
                              hipStream_t stream) {
    const float* rgb = (const float*)d_in[0];
    float* out = (float*)d_out;
    jpeg_dct<<<dim3(2048), dim3(192), 0, stream>>>(rgb, out);
}